// Round 3
// baseline (157.637 us; speedup 1.0000x reference)
//
#include <hip/hip_runtime.h>

// PreEncoder float2bit: each input float -> 16 outputs in {-1, +1}.
// Equivalent to truncated fp16-style bit extraction with wrap-around 5-bit
// exponent:  w = s<<15 | ((E+15)&31)<<10 | (mant23>>13)
//   s = sign(f + 0.001) quirk ((f+0.001)==0 -> output 0.0), zero -> all 0,
//   NaN -> 0x7E00, +inf -> 0x7C00, -inf -> 0xFC00.
// One thread per output float4 (4 bits of one input element): coalesced 1KB
// stores per wave; input loads are 4-way duplicated but merged by the
// coalescer. Stores use the nontemporal (nt) policy — output is write-once
// streaming, don't churn L2. NOTE: the nontemporal builtin needs a clang
// native vector type, not HIP's float4 class.

typedef float vfloat4 __attribute__((ext_vector_type(4)));

__global__ __launch_bounds__(256) void preencoder_f2b_kernel(
    const float* __restrict__ x, vfloat4* __restrict__ out, int n4) {
  int t = blockIdx.x * blockDim.x + threadIdx.x;
  if (t >= n4) return;

  int i = t >> 2;   // input element
  int c = t & 3;    // which group of 4 bits

  float f = x[i];
  unsigned u = __float_as_uint(f);
  unsigned a = u & 0x7FFFFFFFu;

  unsigned w;
  bool sign_half = false;  // (f + 0.001f) == 0 exactly -> s = 0.5 -> output 0.0

  if (a > 0x7F800000u) {
    w = 0x7E00u;                           // NaN pattern
  } else if (a == 0x7F800000u) {
    w = (u >> 31) ? 0xFC00u : 0x7C00u;     // +/- inf
  } else {
    if (a == 0u) {
      w = 0u;                              // zero: e_dec = 0, mantissa 0
    } else {
      int e8 = (int)(a >> 23);
      int E;
      unsigned mant;
      if (e8 != 0) {
        E = e8 - 127;                      // normal
        mant = a & 0x7FFFFFu;
      } else {
        int p = 31 - __clz((int)a);        // subnormal: exact normalize
        E = p - 149;
        mant = (a << (23 - p)) & 0x7FFFFFu;
      }
      // low 5 two's-complement bits of (E+15) == floored-div/mod semantics;
      // top 10 mantissa bits, truncated.
      w = ((unsigned)((E + 15) & 31) << 10) | (mant >> 13);
    }
    float tt = f + 0.001f;
    if (tt < 0.0f) {
      w |= 0x8000u;
    } else if (tt == 0.0f) {
      sign_half = true;
    }
  }

  int hi = 15 - 4 * c;  // bit positions hi..hi-3 map to outputs 4c..4c+3
  vfloat4 o;
  o.x = ((w >> hi) & 1u) ? 1.0f : -1.0f;
  o.y = ((w >> (hi - 1)) & 1u) ? 1.0f : -1.0f;
  o.z = ((w >> (hi - 2)) & 1u) ? 1.0f : -1.0f;
  o.w = ((w >> (hi - 3)) & 1u) ? 1.0f : -1.0f;
  if (c == 0 && sign_half) o.x = 0.0f;

  __builtin_nontemporal_store(o, &out[t]);
}

extern "C" void kernel_launch(void* const* d_in, const int* in_sizes, int n_in,
                              void* d_out, int out_size, void* d_ws, size_t ws_size,
                              hipStream_t stream) {
  const float* x = (const float*)d_in[0];
  vfloat4* out = (vfloat4*)d_out;
  int n4 = out_size / 4;  // one float4 per thread
  int threads = 256;
  int blocks = (n4 + threads - 1) / threads;
  preencoder_f2b_kernel<<<blocks, threads, 0, stream>>>(x, out, n4);
}

// Round 4
// 143.124 us; speedup vs baseline: 1.1014x; 1.1014x over previous
//
#include <hip/hip_runtime.h>

// PreEncoder float2bit: each input float -> 16 outputs in {-1, +1}.
// Equivalent to truncated fp16-style bit extraction with wrap-around 5-bit
// exponent:  w = s<<15 | ((E+15)&31)<<10 | (mant23>>13)
//   s = sign(f + 0.001) quirk ((f+0.001)==0 -> output 0.0), zero -> all 0,
//   NaN -> 0x7E00, +inf -> 0x7C00, -inf -> 0xFC00.
//
// R3 lesson: nontemporal stores regressed (150.5 -> 157.6 us) — reverted.
// This round: persistent grid-stride shape (2048 blocks x 256 = exactly
// max co-residency on 256 CUs), one float4 chunk per loop iteration.
// Stores stay perfectly coalesced (1 KB/wave contiguous); the grid sweeps
// the output in sequential 8 MiB windows like the 6.3 TB/s fill kernel.

typedef float vfloat4 __attribute__((ext_vector_type(4)));

__global__ __launch_bounds__(256) void preencoder_f2b_kernel(
    const float* __restrict__ x, vfloat4* __restrict__ out, int n4) {
  const int stride = gridDim.x * blockDim.x;
  for (int t = blockIdx.x * blockDim.x + threadIdx.x; t < n4; t += stride) {
    int i = t >> 2;   // input element
    int c = t & 3;    // which group of 4 bits

    float f = x[i];
    unsigned u = __float_as_uint(f);
    unsigned a = u & 0x7FFFFFFFu;

    unsigned w;
    bool sign_half = false;  // (f+0.001f)==0 exactly -> s=0.5 -> output 0.0

    if (a > 0x7F800000u) {
      w = 0x7E00u;                           // NaN pattern
    } else if (a == 0x7F800000u) {
      w = (u >> 31) ? 0xFC00u : 0x7C00u;     // +/- inf
    } else {
      if (a == 0u) {
        w = 0u;                              // zero: e_dec = 0, mantissa 0
      } else {
        int e8 = (int)(a >> 23);
        int E;
        unsigned mant;
        if (e8 != 0) {
          E = e8 - 127;                      // normal
          mant = a & 0x7FFFFFu;
        } else {
          int p = 31 - __clz((int)a);        // subnormal: exact normalize
          E = p - 149;
          mant = (a << (23 - p)) & 0x7FFFFFu;
        }
        // low 5 two's-complement bits of (E+15) == floored-div/mod semantics;
        // top 10 mantissa bits, truncated.
        w = ((unsigned)((E + 15) & 31) << 10) | (mant >> 13);
      }
      float tt = f + 0.001f;
      if (tt < 0.0f) {
        w |= 0x8000u;
      } else if (tt == 0.0f) {
        sign_half = true;
      }
    }

    int hi = 15 - 4 * c;  // bit positions hi..hi-3 map to outputs 4c..4c+3
    vfloat4 o;
    o.x = ((w >> hi) & 1u) ? 1.0f : -1.0f;
    o.y = ((w >> (hi - 1)) & 1u) ? 1.0f : -1.0f;
    o.z = ((w >> (hi - 2)) & 1u) ? 1.0f : -1.0f;
    o.w = ((w >> (hi - 3)) & 1u) ? 1.0f : -1.0f;
    if (c == 0 && sign_half) o.x = 0.0f;

    out[t] = o;
  }
}

extern "C" void kernel_launch(void* const* d_in, const int* in_sizes, int n_in,
                              void* d_out, int out_size, void* d_ws, size_t ws_size,
                              hipStream_t stream) {
  const float* x = (const float*)d_in[0];
  vfloat4* out = (vfloat4*)d_out;
  int n4 = out_size / 4;  // one float4 per chunk
  int threads = 256;
  // 2048 blocks x 4 waves = 8192 waves = exactly 32 waves/CU on 256 CUs.
  int blocks = 2048;
  preencoder_f2b_kernel<<<blocks, threads, 0, stream>>>(x, out, n4);
}

// Round 5
// 141.793 us; speedup vs baseline: 1.1117x; 1.0094x over previous
//
#include <hip/hip_runtime.h>

// PreEncoder float2bit: each input float -> 16 outputs in {-1, +1}.
// Equivalent to truncated fp16-style bit extraction with wrap-around 5-bit
// exponent:  w = s<<15 | ((E+15)&31)<<10 | (mant23>>13)
//   s = sign(f + 0.001) quirk ((f+0.001)==0 -> output 0.0), zero -> all 0,
//   NaN -> 0x7E00, +inf -> 0x7C00, -inf -> 0xFC00.
//
// Ladder: R1 one-shot grid 150.5 us; R3 nt-stores 157.6 (reverted);
// R4 persistent grid-stride 143.1. This round: unroll x4 with independent
// chunks (t, t+S, t+2S, t+3S) — 4 loads hoisted, 4 coalesced 1KB/wave
// stores issued back-to-back per wave iteration (more stores in flight,
// like the 6.5 TB/s fill kernel). Output ±1 via single XOR on the sign bit.

typedef float vfloat4 __attribute__((ext_vector_type(4)));

__device__ __forceinline__ vfloat4 decode_chunk(float f, int c) {
  unsigned u = __float_as_uint(f);
  unsigned a = u & 0x7FFFFFFFu;

  unsigned w;
  bool sign_half = false;  // (f+0.001f)==0 exactly -> s=0.5 -> output 0.0

  if (a > 0x7F800000u) {
    w = 0x7E00u;                           // NaN pattern
  } else if (a == 0x7F800000u) {
    w = (u >> 31) ? 0xFC00u : 0x7C00u;     // +/- inf
  } else {
    if (a == 0u) {
      w = 0u;                              // zero: e_dec = 0, mantissa 0
    } else {
      int e8 = (int)(a >> 23);
      int E;
      unsigned mant;
      if (e8 != 0) {
        E = e8 - 127;                      // normal
        mant = a & 0x7FFFFFu;
      } else {
        int p = 31 - __clz((int)a);        // subnormal: exact normalize
        E = p - 149;
        mant = (a << (23 - p)) & 0x7FFFFFu;
      }
      // low 5 two's-complement bits of (E+15) == floored-div/mod semantics;
      // top 10 mantissa bits, truncated.
      w = ((unsigned)((E + 15) & 31) << 10) | (mant >> 13);
    }
    float tt = f + 0.001f;
    if (tt < 0.0f) {
      w |= 0x8000u;
    } else if (tt == 0.0f) {
      sign_half = true;
    }
  }

  int hi = 15 - 4 * c;  // bit positions hi..hi-3 map to outputs 4c..4c+3
  // +1.0f = 0x3F800000, -1.0f = 0xBF800000: flip sign bit when bit==0.
  vfloat4 o;
  o.x = __uint_as_float(0x3F800000u ^ ((((w >> hi) & 1u) ^ 1u) << 31));
  o.y = __uint_as_float(0x3F800000u ^ ((((w >> (hi - 1)) & 1u) ^ 1u) << 31));
  o.z = __uint_as_float(0x3F800000u ^ ((((w >> (hi - 2)) & 1u) ^ 1u) << 31));
  o.w = __uint_as_float(0x3F800000u ^ ((((w >> (hi - 3)) & 1u) ^ 1u) << 31));
  if (c == 0 && sign_half) o.x = 0.0f;
  return o;
}

__global__ __launch_bounds__(256) void preencoder_f2b_kernel(
    const float* __restrict__ x, vfloat4* __restrict__ out, int n4) {
  const int S = gridDim.x * blockDim.x;
  int t = blockIdx.x * blockDim.x + threadIdx.x;

  // Main loop: 4 independent chunks per iteration (n4/S = 16 -> 4 rounds).
  for (; t + 3 * S < n4; t += 4 * S) {
    int t1 = t + S, t2 = t + 2 * S, t3 = t + 3 * S;
    float f0 = x[t >> 2];
    float f1 = x[t1 >> 2];
    float f2 = x[t2 >> 2];
    float f3 = x[t3 >> 2];
    vfloat4 o0 = decode_chunk(f0, t & 3);
    vfloat4 o1 = decode_chunk(f1, t1 & 3);
    vfloat4 o2 = decode_chunk(f2, t2 & 3);
    vfloat4 o3 = decode_chunk(f3, t3 & 3);
    out[t]  = o0;
    out[t1] = o1;
    out[t2] = o2;
    out[t3] = o3;
  }
  // Tail
  for (; t < n4; t += S) {
    out[t] = decode_chunk(x[t >> 2], t & 3);
  }
}

extern "C" void kernel_launch(void* const* d_in, const int* in_sizes, int n_in,
                              void* d_out, int out_size, void* d_ws, size_t ws_size,
                              hipStream_t stream) {
  const float* x = (const float*)d_in[0];
  vfloat4* out = (vfloat4*)d_out;
  int n4 = out_size / 4;  // one float4 per chunk
  int threads = 256;
  // 2048 blocks x 4 waves = 8192 waves = exactly 32 waves/CU on 256 CUs.
  int blocks = 2048;
  preencoder_f2b_kernel<<<blocks, threads, 0, stream>>>(x, out, n4);
}

// Round 6
// 141.056 us; speedup vs baseline: 1.1175x; 1.0052x over previous
//
#include <hip/hip_runtime.h>
#include <hip/hip_fp16.h>

// PreEncoder float2bit: each input float -> 16 outputs in {-1, +1}.
// w = s<<15 | ((E+15)&31)<<10 | (mant23>>13), with s from sign(f+0.001)
// (f+0.001==0 -> s=0.5 -> output 0.0), zero -> all 0, NaN -> 0x7E00,
// +inf -> 0x7C00, -inf -> 0xFC00.
//
// Ladder: R1 150.5 | R3 nt-store 157.6 (revert) | R4 grid-stride 143.1 |
// R5 unroll x4 141.8. This round:
//  (a) software-pipelined loads: prefetch round k+1's 4 inputs before
//      decoding round k (input loads are L2-cold; dependent chain was
//      barely hidden at 8 waves/SIMD).
//  (b) leaner decode: for 2^-14 <= |f| < 2^16, masking mantissa bits <13
//      makes v_cvt_f16_f32 BIT-EXACT equal to w (value exactly fp16-
//      representable -> no rounding). Rare cases take the integer path.
//  (c) sign OR hoisted: correct for all patterns (NaN cmp false, -inf
//      idempotent); ±1 built with shift/and/xor on 0xBF800000.

typedef float vfloat4 __attribute__((ext_vector_type(4)));

__device__ __forceinline__ unsigned decode_w(float f) {
  unsigned u = __float_as_uint(f);
  unsigned a = u & 0x7FFFFFFFu;
  unsigned w;
  if (__builtin_expect(a - 0x38800000u < 0x0F000000u, 1)) {
    // 2^-14 <= |f| < 2^16: truncate mantissa to 10 bits, convert exactly.
    float tm = __uint_as_float(a & 0xFFFFE000u);
    w = (unsigned)__half_as_ushort(__float2half(tm));
  } else if (a > 0x7F800000u) {
    w = 0x7E00u;                       // NaN pattern (s stays 0: NaN cmp false)
  } else if (a == 0x7F800000u) {
    w = 0x7C00u;                       // inf; -inf gets sign bit below
  } else if (a == 0u) {
    w = 0u;                            // zero
  } else {
    int e8 = (int)(a >> 23);
    int E; unsigned mant;
    if (e8 != 0) {
      E = e8 - 127;                    // normal out of fp16 range
      mant = a & 0x7FFFFFu;
    } else {
      int p = 31 - __clz((int)a);      // fp32 subnormal: exact normalize
      E = p - 149;
      mant = (a << (23 - p)) & 0x7FFFFFu;
    }
    // low 5 two's-complement bits of (E+15) == floored-div/mod semantics.
    w = ((unsigned)((E + 15) & 31) << 10) | (mant >> 13);
  }
  float tt = f + 0.001f;
  if (tt < 0.0f) w |= 0x8000u;         // sign quirk, valid for ALL patterns
  return w;
}

__device__ __forceinline__ vfloat4 extract4(unsigned w, int sh, bool szero) {
  unsigned nib = w >> sh;              // chunk's 4 bits at positions 3..0
  vfloat4 o;
  o.x = __uint_as_float(0xBF800000u ^ ((nib << 28) & 0x80000000u));
  o.y = __uint_as_float(0xBF800000u ^ ((nib << 29) & 0x80000000u));
  o.z = __uint_as_float(0xBF800000u ^ ((nib << 30) & 0x80000000u));
  o.w = __uint_as_float(0xBF800000u ^ (nib << 31));
  if (szero) o.x = 0.0f;               // f == -0.001 exactly -> s = 0.5 -> 0.0
  return o;
}

__global__ __launch_bounds__(256) void preencoder_f2b_kernel(
    const float* __restrict__ x, vfloat4* __restrict__ out, int n4) {
  const int S = gridDim.x * blockDim.x;
  const int tid = blockIdx.x * blockDim.x + threadIdx.x;
  const int c = tid & 3;               // chunk-within-element (S % 4 == 0)
  const int sh = 12 - 4 * c;

  if (n4 == 16 * S) {
    // Specialized: exactly 16 chunks/thread, 4 rounds of 4, pipelined.
    const int S4 = S >> 2;             // element stride between j-slots
    int t = tid;                       // chunk index, round base
    int e = tid >> 2;                  // element index for j=0
    float f[4];
#pragma unroll
    for (int j = 0; j < 4; ++j) f[j] = x[e + j * S4];

#pragma unroll
    for (int r = 0; r < 4; ++r) {
      float g[4] = {0.0f, 0.0f, 0.0f, 0.0f};
      if (r < 3) {
        int en = e + S;                // next round's elements
#pragma unroll
        for (int j = 0; j < 4; ++j) g[j] = x[en + j * S4];
      }
#pragma unroll
      for (int j = 0; j < 4; ++j) {
        bool szero = (c == 0) && (f[j] == -0.001f);
        out[t + j * S] = extract4(decode_w(f[j]), sh, szero);
      }
#pragma unroll
      for (int j = 0; j < 4; ++j) f[j] = g[j];
      e += S;
      t += 4 * S;
    }
  } else {
    // Generic fallback (any n4)
    for (int t = tid; t < n4; t += S) {
      int cc = t & 3;
      bool szero = (cc == 0) && (x[t >> 2] == -0.001f);
      out[t] = extract4(decode_w(x[t >> 2]), 12 - 4 * cc, szero);
    }
  }
}

extern "C" void kernel_launch(void* const* d_in, const int* in_sizes, int n_in,
                              void* d_out, int out_size, void* d_ws, size_t ws_size,
                              hipStream_t stream) {
  const float* x = (const float*)d_in[0];
  vfloat4* out = (vfloat4*)d_out;
  int n4 = out_size / 4;               // one float4 per chunk
  int threads = 256;
  int blocks = 2048;                   // 8192 waves = 32/CU on 256 CUs
  preencoder_f2b_kernel<<<blocks, threads, 0, stream>>>(x, out, n4);
}